// Round 2
// baseline (413.465 us; speedup 1.0000x reference)
//
#include <hip/hip_runtime.h>
#include <hip/hip_bf16.h>

#define B_ 4
#define S_ 4096
#define D_ 1024
#define H_ 128

typedef _Float16 half8 __attribute__((ext_vector_type(8)));
typedef _Float16 half4v __attribute__((ext_vector_type(4)));
typedef float float4v __attribute__((ext_vector_type(4)));

// ---------------- kernel 1: W[k][n] fp32 -> WT[w][n][k] f16 ----------------
__global__ __launch_bounds__(256) void k_cvt_w(const float* __restrict__ Wq,
                                               const float* __restrict__ Wk,
                                               const float* __restrict__ Wv,
                                               _Float16* __restrict__ WT) {
    const float* W = blockIdx.y == 0 ? Wq : (blockIdx.y == 1 ? Wk : Wv);
    int idx = blockIdx.x * 256 + threadIdx.x;   // 0..131071  (grid.x = 512)
    int k = idx >> 7, n = idx & 127;
    WT[(size_t)blockIdx.y * (H_ * D_) + (size_t)n * D_ + k] = (_Float16)W[idx];
}

// ---------------- kernel 2: QKV projection GEMM ----------------
// X[f32][16384][1024] @ W -> Qf/Kf f16 [16384][128] (q pre-scaled by 1/sqrt(H)),
// V stored transposed: VTf[b][h][s] f16.
__global__ __launch_bounds__(256) void k_proj(const float* __restrict__ X,
                                              const _Float16* __restrict__ WT,
                                              const float* __restrict__ bq,
                                              const float* __restrict__ bk,
                                              const float* __restrict__ bv,
                                              _Float16* __restrict__ Qf,
                                              _Float16* __restrict__ Kf,
                                              _Float16* __restrict__ VTf) {
    __shared__ _Float16 As[128][72];   // x tile, +8 pad
    __shared__ _Float16 Bs[128][72];   // wT tile ([n][k]), +8 pad

    const int t    = threadIdx.x;
    const int w    = blockIdx.x;          // 0=q 1=k 2=v
    const int m0   = blockIdx.y * 128;
    const int lane = t & 63, wid = t >> 6;
    const int lo   = lane & 15, hi = lane >> 4;
    const int wr   = wid >> 1, wc = wid & 1;

    const _Float16* Wt = WT + (size_t)w * (H_ * D_);

    float4v acc[4][4];
#pragma unroll
    for (int mt = 0; mt < 4; ++mt)
#pragma unroll
        for (int nt = 0; nt < 4; ++nt) acc[mt][nt] = {0.f, 0.f, 0.f, 0.f};

    for (int it = 0; it < 16; ++it) {
        const int k0 = it * 64;
        __syncthreads();
#pragma unroll
        for (int pass = 0; pass < 4; ++pass) {
            const int r = pass * 32 + (t >> 3);
            const int c = (t & 7) * 8;
            float4v a0 = *(const float4v*)(X + (size_t)(m0 + r) * D_ + k0 + c);
            float4v a1 = *(const float4v*)(X + (size_t)(m0 + r) * D_ + k0 + c + 4);
            half8 ha;
            ha[0] = (_Float16)a0[0]; ha[1] = (_Float16)a0[1];
            ha[2] = (_Float16)a0[2]; ha[3] = (_Float16)a0[3];
            ha[4] = (_Float16)a1[0]; ha[5] = (_Float16)a1[1];
            ha[6] = (_Float16)a1[2]; ha[7] = (_Float16)a1[3];
            *(half8*)(&As[r][c]) = ha;
            *(half8*)(&Bs[r][c]) = *(const half8*)(Wt + (size_t)r * D_ + k0 + c);
        }
        __syncthreads();
#pragma unroll
        for (int kk = 0; kk < 2; ++kk) {
            half8 af[4], bf[4];
#pragma unroll
            for (int mt = 0; mt < 4; ++mt)
                af[mt] = *(const half8*)(&As[wr * 64 + mt * 16 + lo][kk * 32 + hi * 8]);
#pragma unroll
            for (int nt = 0; nt < 4; ++nt)
                bf[nt] = *(const half8*)(&Bs[wc * 64 + nt * 16 + lo][kk * 32 + hi * 8]);
#pragma unroll
            for (int mt = 0; mt < 4; ++mt)
#pragma unroll
                for (int nt = 0; nt < 4; ++nt)
                    acc[mt][nt] = __builtin_amdgcn_mfma_f32_16x16x32_f16(
                        af[mt], bf[nt], acc[mt][nt], 0, 0, 0);
        }
    }

    const float* bias = (w == 0) ? bq : ((w == 1) ? bk : bv);
    const float scale = (w == 0) ? 0.08838834764831845f : 1.0f;  // 1/sqrt(128)
#pragma unroll
    for (int mt = 0; mt < 4; ++mt)
#pragma unroll
        for (int nt = 0; nt < 4; ++nt) {
            const int n     = wc * 64 + nt * 16 + lo;
            const float bn  = bias[n];
            const int mbase = m0 + wr * 64 + mt * 16 + 4 * hi;
            if (w == 2) {
                const int bb = mbase >> 12;        // batch
                const int s0 = mbase & (S_ - 1);   // seq pos
                half4v hv;
#pragma unroll
                for (int j = 0; j < 4; ++j) hv[j] = (_Float16)(acc[mt][nt][j] + bn);
                *(half4v*)(VTf + (size_t)bb * (H_ * S_) + (size_t)n * S_ + s0) = hv;
            } else {
                _Float16* dst = (w == 0) ? Qf : Kf;
#pragma unroll
                for (int j = 0; j < 4; ++j)
                    dst[(size_t)(mbase + j) * H_ + n] =
                        (_Float16)((acc[mt][nt][j] + bn) * scale);
            }
        }
}

// ---------------- kernel 3: causal flash attention ----------------
// 1 wave per 16-query tile. Swapped QK^T: scores land lane-local per query.
// Permuted K-row loads make score frags concatenate into the PV x32 B-operand.
// OUTPUT IS FP32 (reference returns float32).
__global__ __launch_bounds__(64) void k_attn(const _Float16* __restrict__ Qf,
                                             const _Float16* __restrict__ Kf,
                                             const _Float16* __restrict__ VTf,
                                             float* __restrict__ Out) {
    const int lane = threadIdx.x;
    const int lo = lane & 15, hi = lane >> 4;
    const int b  = blockIdx.y;
    const int qt = (int)gridDim.x - 1 - (int)blockIdx.x;  // heavy tiles first
    const int q0 = qt * 16;

    const _Float16* Qb = Qf  + (size_t)b * (S_ * H_);
    const _Float16* Kb = Kf  + (size_t)b * (S_ * H_);
    const _Float16* Vb = VTf + (size_t)b * (H_ * S_);

    half8 qf[4];
#pragma unroll
    for (int kk = 0; kk < 4; ++kk)
        qf[kk] = *(const half8*)(Qb + (size_t)(q0 + lo) * H_ + kk * 32 + hi * 8);

    float4v o[8];
#pragma unroll
    for (int hc = 0; hc < 8; ++hc) o[hc] = {0.f, 0.f, 0.f, 0.f};
    float m = -INFINITY, l = 0.f;

    const int permbase = ((lo >> 2) << 3) + (lo & 3);       // key row permutation
    const int ntiles = (q0 + 47) >> 5;                      // keys 0..q0+15, 32/tile
    const int nfull  = (q0 >= 31) ? (((q0 - 31) >> 5) + 1) : 0;

    for (int tt = 0; tt < ntiles; ++tt) {
        const int k0 = tt << 5;
        float4v s0 = {0.f, 0.f, 0.f, 0.f}, s1 = {0.f, 0.f, 0.f, 0.f};
        const _Float16* Kr0 = Kb + (size_t)(k0 + permbase) * H_;
        const _Float16* Kr1 = Kr0 + 4 * H_;
#pragma unroll
        for (int kk = 0; kk < 4; ++kk) {
            half8 kf0 = *(const half8*)(Kr0 + kk * 32 + hi * 8);
            s0 = __builtin_amdgcn_mfma_f32_16x16x32_f16(kf0, qf[kk], s0, 0, 0, 0);
            half8 kf1 = *(const half8*)(Kr1 + kk * 32 + hi * 8);
            s1 = __builtin_amdgcn_mfma_f32_16x16x32_f16(kf1, qf[kk], s1, 0, 0, 0);
        }
        // s0[j] = S[q0+lo][k0+8hi+j], s1[j] = S[q0+lo][k0+8hi+4+j]
        if (tt >= nfull) {
#pragma unroll
            for (int j = 0; j < 4; ++j) {
                if (k0 + 8 * hi + j     > q0 + lo) s0[j] = -INFINITY;
                if (k0 + 8 * hi + 4 + j > q0 + lo) s1[j] = -INFINITY;
            }
        }
        float tmax = fmaxf(fmaxf(fmaxf(s0[0], s0[1]), fmaxf(s0[2], s0[3])),
                           fmaxf(fmaxf(s1[0], s1[1]), fmaxf(s1[2], s1[3])));
        tmax = fmaxf(tmax, __shfl_xor(tmax, 16));
        tmax = fmaxf(tmax, __shfl_xor(tmax, 32));
        const float mnew  = fmaxf(m, tmax);
        const float alpha = __expf(m - mnew);
        float p0 = __expf(s0[0] - mnew), p1 = __expf(s0[1] - mnew);
        float p2 = __expf(s0[2] - mnew), p3 = __expf(s0[3] - mnew);
        float p4 = __expf(s1[0] - mnew), p5 = __expf(s1[1] - mnew);
        float p6 = __expf(s1[2] - mnew), p7 = __expf(s1[3] - mnew);
        float ts = ((p0 + p1) + (p2 + p3)) + ((p4 + p5) + (p6 + p7));
        ts += __shfl_xor(ts, 16);
        ts += __shfl_xor(ts, 32);
        l = l * alpha + ts;
        m = mnew;
#pragma unroll
        for (int hc = 0; hc < 8; ++hc) {
            o[hc][0] *= alpha; o[hc][1] *= alpha;
            o[hc][2] *= alpha; o[hc][3] *= alpha;
        }
        half8 pf;
        pf[0] = (_Float16)p0; pf[1] = (_Float16)p1; pf[2] = (_Float16)p2; pf[3] = (_Float16)p3;
        pf[4] = (_Float16)p4; pf[5] = (_Float16)p5; pf[6] = (_Float16)p6; pf[7] = (_Float16)p7;
#pragma unroll
        for (int hc = 0; hc < 8; ++hc) {
            half8 vf = *(const half8*)(Vb + (size_t)(hc * 16 + lo) * S_ + k0 + hi * 8);
            o[hc] = __builtin_amdgcn_mfma_f32_16x16x32_f16(vf, pf, o[hc], 0, 0, 0);
        }
    }

    const float inv = 1.0f / l;
    float* Ob = Out + ((size_t)b * S_ + q0 + lo) * H_;
#pragma unroll
    for (int hc = 0; hc < 8; ++hc) {
        float4v ov;
#pragma unroll
        for (int j = 0; j < 4; ++j) ov[j] = o[hc][j] * inv;
        *(float4v*)(Ob + hc * 16 + 4 * hi) = ov;
    }
}

extern "C" void kernel_launch(void* const* d_in, const int* in_sizes, int n_in,
                              void* d_out, int out_size, void* d_ws, size_t ws_size,
                              hipStream_t stream) {
    const float* x  = (const float*)d_in[0];
    const float* Wq = (const float*)d_in[1];
    const float* bq = (const float*)d_in[2];
    const float* Wk = (const float*)d_in[3];
    const float* bk = (const float*)d_in[4];
    const float* Wv = (const float*)d_in[5];
    const float* bv = (const float*)d_in[6];
    float* out = (float*)d_out;   // reference output dtype = float32

    char* ws = (char*)d_ws;
    _Float16* WT  = (_Float16*)ws;                       //   786,432 B
    _Float16* Qf  = (_Float16*)(ws + 786432);            // 4,194,304 B
    _Float16* Kf  = (_Float16*)(ws + 786432 + 4194304);
    _Float16* VTf = (_Float16*)(ws + 786432 + 8388608);  // total ~12.8 MB

    hipLaunchKernelGGL(k_cvt_w, dim3(512, 3), dim3(256), 0, stream, Wq, Wk, Wv, WT);
    hipLaunchKernelGGL(k_proj, dim3(3, 128), dim3(256), 0, stream,
                       x, WT, bq, bk, bv, Qf, Kf, VTf);
    hipLaunchKernelGGL(k_attn, dim3(256, 4), dim3(64), 0, stream, Qf, Kf, VTf, out);
}

// Round 3
// 270.800 us; speedup vs baseline: 1.5268x; 1.5268x over previous
//
#include <hip/hip_runtime.h>
#include <hip/hip_bf16.h>

#define B_ 4
#define S_ 4096
#define D_ 1024
#define H_ 128

typedef _Float16 half8 __attribute__((ext_vector_type(8)));
typedef _Float16 half4v __attribute__((ext_vector_type(4)));
typedef float float4v __attribute__((ext_vector_type(4)));

// ---------------- kernel 1: W[k][n] fp32 -> WT[w][n][k] f16 ----------------
__global__ __launch_bounds__(256) void k_cvt_w(const float* __restrict__ Wq,
                                               const float* __restrict__ Wk,
                                               const float* __restrict__ Wv,
                                               _Float16* __restrict__ WT) {
    const float* W = blockIdx.y == 0 ? Wq : (blockIdx.y == 1 ? Wk : Wv);
    int idx = blockIdx.x * 256 + threadIdx.x;   // 0..131071  (grid.x = 512)
    int k = idx >> 7, n = idx & 127;
    WT[(size_t)blockIdx.y * (H_ * D_) + (size_t)n * D_ + k] = (_Float16)W[idx];
}

// ---------------- kernel 2: QKV projection GEMM ----------------
__global__ __launch_bounds__(256) void k_proj(const float* __restrict__ X,
                                              const _Float16* __restrict__ WT,
                                              const float* __restrict__ bq,
                                              const float* __restrict__ bk,
                                              const float* __restrict__ bv,
                                              _Float16* __restrict__ Qf,
                                              _Float16* __restrict__ Kf,
                                              _Float16* __restrict__ VTf) {
    __shared__ _Float16 As[128][72];   // x tile, +8 pad
    __shared__ _Float16 Bs[128][72];   // wT tile ([n][k]), +8 pad

    const int t    = threadIdx.x;
    const int w    = blockIdx.x;          // 0=q 1=k 2=v
    const int m0   = blockIdx.y * 128;
    const int lane = t & 63, wid = t >> 6;
    const int lo   = lane & 15, hi = lane >> 4;
    const int wr   = wid >> 1, wc = wid & 1;

    const _Float16* Wt = WT + (size_t)w * (H_ * D_);

    float4v acc[4][4];
#pragma unroll
    for (int mt = 0; mt < 4; ++mt)
#pragma unroll
        for (int nt = 0; nt < 4; ++nt) acc[mt][nt] = {0.f, 0.f, 0.f, 0.f};

    for (int it = 0; it < 16; ++it) {
        const int k0 = it * 64;
        __syncthreads();
#pragma unroll
        for (int pass = 0; pass < 4; ++pass) {
            const int r = pass * 32 + (t >> 3);
            const int c = (t & 7) * 8;
            float4v a0 = *(const float4v*)(X + (size_t)(m0 + r) * D_ + k0 + c);
            float4v a1 = *(const float4v*)(X + (size_t)(m0 + r) * D_ + k0 + c + 4);
            half8 ha;
            ha[0] = (_Float16)a0[0]; ha[1] = (_Float16)a0[1];
            ha[2] = (_Float16)a0[2]; ha[3] = (_Float16)a0[3];
            ha[4] = (_Float16)a1[0]; ha[5] = (_Float16)a1[1];
            ha[6] = (_Float16)a1[2]; ha[7] = (_Float16)a1[3];
            *(half8*)(&As[r][c]) = ha;
            *(half8*)(&Bs[r][c]) = *(const half8*)(Wt + (size_t)r * D_ + k0 + c);
        }
        __syncthreads();
#pragma unroll
        for (int kk = 0; kk < 2; ++kk) {
            half8 af[4], bf[4];
#pragma unroll
            for (int mt = 0; mt < 4; ++mt)
                af[mt] = *(const half8*)(&As[wr * 64 + mt * 16 + lo][kk * 32 + hi * 8]);
#pragma unroll
            for (int nt = 0; nt < 4; ++nt)
                bf[nt] = *(const half8*)(&Bs[wc * 64 + nt * 16 + lo][kk * 32 + hi * 8]);
#pragma unroll
            for (int mt = 0; mt < 4; ++mt)
#pragma unroll
                for (int nt = 0; nt < 4; ++nt)
                    acc[mt][nt] = __builtin_amdgcn_mfma_f32_16x16x32_f16(
                        af[mt], bf[nt], acc[mt][nt], 0, 0, 0);
        }
    }

    const float* bias = (w == 0) ? bq : ((w == 1) ? bk : bv);
    const float scale = (w == 0) ? 0.08838834764831845f : 1.0f;  // 1/sqrt(128)
#pragma unroll
    for (int mt = 0; mt < 4; ++mt)
#pragma unroll
        for (int nt = 0; nt < 4; ++nt) {
            const int n     = wc * 64 + nt * 16 + lo;
            const float bn  = bias[n];
            const int mbase = m0 + wr * 64 + mt * 16 + 4 * hi;
            if (w == 2) {
                const int bb = mbase >> 12;        // batch
                const int s0 = mbase & (S_ - 1);   // seq pos
                half4v hv;
#pragma unroll
                for (int j = 0; j < 4; ++j) hv[j] = (_Float16)(acc[mt][nt][j] + bn);
                *(half4v*)(VTf + (size_t)bb * (H_ * S_) + (size_t)n * S_ + s0) = hv;
            } else {
                _Float16* dst = (w == 0) ? Qf : Kf;
#pragma unroll
                for (int j = 0; j < 4; ++j)
                    dst[(size_t)(mbase + j) * H_ + n] =
                        (_Float16)((acc[mt][nt][j] + bn) * scale);
            }
        }
}

// ---------------- kernel 3: causal flash attention, KV-split x4 ----------------
// 4 waves/block, one 16-query tile/block. Wave w handles KV tiles w, w+4, ...
// with its own partial (o, m, l); LDS merge at the end (flash-decode style).
// Running max floored at -1e30 so a fully-masked first tile can't NaN.
__global__ __launch_bounds__(256) void k_attn(const _Float16* __restrict__ Qf,
                                              const _Float16* __restrict__ Kf,
                                              const _Float16* __restrict__ VTf,
                                              float* __restrict__ Out) {
    __shared__ float sm_m[4][16];
    __shared__ float sm_l[4][16];
    __shared__ float sm_o[4][128][17];   // [wave][h][q], +1 pad

    const int t    = threadIdx.x;
    const int lane = t & 63, wid = t >> 6;
    const int lo = lane & 15, hi = lane >> 4;
    const int b  = blockIdx.y;
    const int qt = (int)gridDim.x - 1 - (int)blockIdx.x;  // heavy tiles first
    const int q0 = qt * 16;

    const _Float16* Qb = Qf  + (size_t)b * (S_ * H_);
    const _Float16* Kb = Kf  + (size_t)b * (S_ * H_);
    const _Float16* Vb = VTf + (size_t)b * (H_ * S_);

    half8 qf[4];
#pragma unroll
    for (int kk = 0; kk < 4; ++kk)
        qf[kk] = *(const half8*)(Qb + (size_t)(q0 + lo) * H_ + kk * 32 + hi * 8);

    float4v o[8];
#pragma unroll
    for (int hc = 0; hc < 8; ++hc) o[hc] = {0.f, 0.f, 0.f, 0.f};
    float m = -1e30f, l = 0.f;

    const int permbase = ((lo >> 2) << 3) + (lo & 3);       // key row permutation
    const int ntiles = (q0 + 47) >> 5;                      // keys 0..q0+15, 32/tile
    const int nfull  = (q0 >= 31) ? (((q0 - 31) >> 5) + 1) : 0;

    for (int tt = wid; tt < ntiles; tt += 4) {
        const int k0 = tt << 5;
        float4v s0 = {0.f, 0.f, 0.f, 0.f}, s1 = {0.f, 0.f, 0.f, 0.f};
        const _Float16* Kr0 = Kb + (size_t)(k0 + permbase) * H_;
        const _Float16* Kr1 = Kr0 + 4 * H_;
#pragma unroll
        for (int kk = 0; kk < 4; ++kk) {
            half8 kf0 = *(const half8*)(Kr0 + kk * 32 + hi * 8);
            s0 = __builtin_amdgcn_mfma_f32_16x16x32_f16(kf0, qf[kk], s0, 0, 0, 0);
            half8 kf1 = *(const half8*)(Kr1 + kk * 32 + hi * 8);
            s1 = __builtin_amdgcn_mfma_f32_16x16x32_f16(kf1, qf[kk], s1, 0, 0, 0);
        }
        // s0[j] = S[q0+lo][k0+8hi+j], s1[j] = S[q0+lo][k0+8hi+4+j]
        if (tt >= nfull) {
#pragma unroll
            for (int j = 0; j < 4; ++j) {
                if (k0 + 8 * hi + j     > q0 + lo) s0[j] = -INFINITY;
                if (k0 + 8 * hi + 4 + j > q0 + lo) s1[j] = -INFINITY;
            }
        }
        float tmax = fmaxf(fmaxf(fmaxf(s0[0], s0[1]), fmaxf(s0[2], s0[3])),
                           fmaxf(fmaxf(s1[0], s1[1]), fmaxf(s1[2], s1[3])));
        tmax = fmaxf(tmax, __shfl_xor(tmax, 16));
        tmax = fmaxf(tmax, __shfl_xor(tmax, 32));
        const float mnew  = fmaxf(fmaxf(m, tmax), -1e30f);  // finite floor: no NaN
        const float alpha = __expf(m - mnew);
        float p0 = __expf(s0[0] - mnew), p1 = __expf(s0[1] - mnew);
        float p2 = __expf(s0[2] - mnew), p3 = __expf(s0[3] - mnew);
        float p4 = __expf(s1[0] - mnew), p5 = __expf(s1[1] - mnew);
        float p6 = __expf(s1[2] - mnew), p7 = __expf(s1[3] - mnew);
        float ts = ((p0 + p1) + (p2 + p3)) + ((p4 + p5) + (p6 + p7));
        ts += __shfl_xor(ts, 16);
        ts += __shfl_xor(ts, 32);
        l = l * alpha + ts;
        m = mnew;
#pragma unroll
        for (int hc = 0; hc < 8; ++hc) {
            o[hc][0] *= alpha; o[hc][1] *= alpha;
            o[hc][2] *= alpha; o[hc][3] *= alpha;
        }
        half8 pf;
        pf[0] = (_Float16)p0; pf[1] = (_Float16)p1; pf[2] = (_Float16)p2; pf[3] = (_Float16)p3;
        pf[4] = (_Float16)p4; pf[5] = (_Float16)p5; pf[6] = (_Float16)p6; pf[7] = (_Float16)p7;
#pragma unroll
        for (int hc = 0; hc < 8; ++hc) {
            half8 vf = *(const half8*)(Vb + (size_t)(hc * 16 + lo) * S_ + k0 + hi * 8);
            o[hc] = __builtin_amdgcn_mfma_f32_16x16x32_f16(vf, pf, o[hc], 0, 0, 0);
        }
    }

    // ---- merge the 4 KV-split partials ----
    sm_m[wid][lo] = m;      // lanes with equal lo write identical values
    sm_l[wid][lo] = l;
#pragma unroll
    for (int hc = 0; hc < 8; ++hc)
#pragma unroll
        for (int j = 0; j < 4; ++j)
            sm_o[wid][hc * 16 + 4 * hi + j][lo] = o[hc][j];
    __syncthreads();

    const float m0_ = sm_m[0][lo], m1_ = sm_m[1][lo];
    const float m2_ = sm_m[2][lo], m3_ = sm_m[3][lo];
    const float M = fmaxf(fmaxf(m0_, m1_), fmaxf(m2_, m3_));
    const float w0 = __expf(m0_ - M), w1 = __expf(m1_ - M);
    const float w2 = __expf(m2_ - M), w3 = __expf(m3_ - M);
    const float L = sm_l[0][lo] * w0 + sm_l[1][lo] * w1 +
                    sm_l[2][lo] * w2 + sm_l[3][lo] * w3;
    const float inv = 1.0f / L;

    float* Ob = Out + ((size_t)b * S_ + q0 + lo) * H_;
#pragma unroll
    for (int g = 0; g < 2; ++g) {
        const int hc = wid * 2 + g;     // wave w finalizes head-chunks 2w, 2w+1
        float4v ov;
#pragma unroll
        for (int j = 0; j < 4; ++j) {
            const int h = hc * 16 + 4 * hi + j;
            ov[j] = (w0 * sm_o[0][h][lo] + w1 * sm_o[1][h][lo] +
                     w2 * sm_o[2][h][lo] + w3 * sm_o[3][h][lo]) * inv;
        }
        *(float4v*)(Ob + hc * 16 + 4 * hi) = ov;
    }
}

extern "C" void kernel_launch(void* const* d_in, const int* in_sizes, int n_in,
                              void* d_out, int out_size, void* d_ws, size_t ws_size,
                              hipStream_t stream) {
    const float* x  = (const float*)d_in[0];
    const float* Wq = (const float*)d_in[1];
    const float* bq = (const float*)d_in[2];
    const float* Wk = (const float*)d_in[3];
    const float* bk = (const float*)d_in[4];
    const float* Wv = (const float*)d_in[5];
    const float* bv = (const float*)d_in[6];
    float* out = (float*)d_out;   // reference output dtype = float32

    char* ws = (char*)d_ws;
    _Float16* WT  = (_Float16*)ws;                       //   786,432 B
    _Float16* Qf  = (_Float16*)(ws + 786432);            // 4,194,304 B
    _Float16* Kf  = (_Float16*)(ws + 786432 + 4194304);
    _Float16* VTf = (_Float16*)(ws + 786432 + 8388608);  // total ~12.8 MB

    hipLaunchKernelGGL(k_cvt_w, dim3(512, 3), dim3(256), 0, stream, Wq, Wk, Wv, WT);
    hipLaunchKernelGGL(k_proj, dim3(3, 128), dim3(256), 0, stream,
                       x, WT, bq, bk, bv, Qf, Kf, VTf);
    hipLaunchKernelGGL(k_attn, dim3(256, 4), dim3(256), 0, stream, Qf, Kf, VTf, out);
}

// Round 4
// 110.026 us; speedup vs baseline: 3.7579x; 2.4612x over previous
//
#include <hip/hip_runtime.h>
#include <hip/hip_bf16.h>

#define B_ 4
#define S_ 4096
#define D_ 1024
#define H_ 128

typedef _Float16 half8 __attribute__((ext_vector_type(8)));
typedef _Float16 half4v __attribute__((ext_vector_type(4)));
typedef float float4v __attribute__((ext_vector_type(4)));

// ---------------- kernel 1: W[k][n] fp32 -> WT[w][n][k] f16 ----------------
__global__ __launch_bounds__(256) void k_cvt_w(const float* __restrict__ Wq,
                                               const float* __restrict__ Wk,
                                               const float* __restrict__ Wv,
                                               _Float16* __restrict__ WT) {
    const float* W = blockIdx.y == 0 ? Wq : (blockIdx.y == 1 ? Wk : Wv);
    int idx = blockIdx.x * 256 + threadIdx.x;   // 0..131071  (grid.x = 512)
    int k = idx >> 7, n = idx & 127;
    WT[(size_t)blockIdx.y * (H_ * D_) + (size_t)n * D_ + k] = (_Float16)W[idx];
}

// ---------------- kernel 2: QKV projection GEMM ----------------
__global__ __launch_bounds__(256) void k_proj(const float* __restrict__ X,
                                              const _Float16* __restrict__ WT,
                                              const float* __restrict__ bq,
                                              const float* __restrict__ bk,
                                              const float* __restrict__ bv,
                                              _Float16* __restrict__ Qf,
                                              _Float16* __restrict__ Kf,
                                              _Float16* __restrict__ VTf) {
    __shared__ _Float16 As[128][72];   // x tile, +8 pad
    __shared__ _Float16 Bs[128][72];   // wT tile ([n][k]), +8 pad

    const int t    = threadIdx.x;
    const int w    = blockIdx.x;          // 0=q 1=k 2=v
    const int m0   = blockIdx.y * 128;
    const int lane = t & 63, wid = t >> 6;
    const int lo   = lane & 15, hi = lane >> 4;
    const int wr   = wid >> 1, wc = wid & 1;

    const _Float16* Wt = WT + (size_t)w * (H_ * D_);

    float4v acc[4][4];
#pragma unroll
    for (int mt = 0; mt < 4; ++mt)
#pragma unroll
        for (int nt = 0; nt < 4; ++nt) acc[mt][nt] = {0.f, 0.f, 0.f, 0.f};

    for (int it = 0; it < 16; ++it) {
        const int k0 = it * 64;
        __syncthreads();
#pragma unroll
        for (int pass = 0; pass < 4; ++pass) {
            const int r = pass * 32 + (t >> 3);
            const int c = (t & 7) * 8;
            float4v a0 = *(const float4v*)(X + (size_t)(m0 + r) * D_ + k0 + c);
            float4v a1 = *(const float4v*)(X + (size_t)(m0 + r) * D_ + k0 + c + 4);
            half8 ha;
            ha[0] = (_Float16)a0[0]; ha[1] = (_Float16)a0[1];
            ha[2] = (_Float16)a0[2]; ha[3] = (_Float16)a0[3];
            ha[4] = (_Float16)a1[0]; ha[5] = (_Float16)a1[1];
            ha[6] = (_Float16)a1[2]; ha[7] = (_Float16)a1[3];
            *(half8*)(&As[r][c]) = ha;
            *(half8*)(&Bs[r][c]) = *(const half8*)(Wt + (size_t)r * D_ + k0 + c);
        }
        __syncthreads();
#pragma unroll
        for (int kk = 0; kk < 2; ++kk) {
            half8 af[4], bf[4];
#pragma unroll
            for (int mt = 0; mt < 4; ++mt)
                af[mt] = *(const half8*)(&As[wr * 64 + mt * 16 + lo][kk * 32 + hi * 8]);
#pragma unroll
            for (int nt = 0; nt < 4; ++nt)
                bf[nt] = *(const half8*)(&Bs[wc * 64 + nt * 16 + lo][kk * 32 + hi * 8]);
#pragma unroll
            for (int mt = 0; mt < 4; ++mt)
#pragma unroll
                for (int nt = 0; nt < 4; ++nt)
                    acc[mt][nt] = __builtin_amdgcn_mfma_f32_16x16x32_f16(
                        af[mt], bf[nt], acc[mt][nt], 0, 0, 0);
        }
    }

    const float* bias = (w == 0) ? bq : ((w == 1) ? bk : bv);
    const float scale = (w == 0) ? 0.08838834764831845f : 1.0f;  // 1/sqrt(128)
#pragma unroll
    for (int mt = 0; mt < 4; ++mt)
#pragma unroll
        for (int nt = 0; nt < 4; ++nt) {
            const int n     = wc * 64 + nt * 16 + lo;
            const float bn  = bias[n];
            const int mbase = m0 + wr * 64 + mt * 16 + 4 * hi;
            if (w == 2) {
                const int bb = mbase >> 12;        // batch
                const int s0 = mbase & (S_ - 1);   // seq pos
                half4v hv;
#pragma unroll
                for (int j = 0; j < 4; ++j) hv[j] = (_Float16)(acc[mt][nt][j] + bn);
                *(half4v*)(VTf + (size_t)bb * (H_ * S_) + (size_t)n * S_ + s0) = hv;
            } else {
                _Float16* dst = (w == 0) ? Qf : Kf;
#pragma unroll
                for (int j = 0; j < 4; ++j)
                    dst[(size_t)(mbase + j) * H_ + n] =
                        (_Float16)((acc[mt][nt][j] + bn) * scale);
            }
        }
}

// ---------------- kernel 3: causal flash attention ----------------
// 32 queries/wave (two 16-row sub-tiles sharing all K/V fragment loads),
// 4-way KV-split across the block's waves, f16 l-normalized partial merge.
// Block decode: batch->XCD-pair affinity (i%8 -> XCD assumption) + zigzag qt
// so CU-paired blocks (i, i+256) get complementary work.
__global__ __launch_bounds__(256) void k_attn(const _Float16* __restrict__ Qf,
                                              const _Float16* __restrict__ Kf,
                                              const _Float16* __restrict__ VTf,
                                              float* __restrict__ Out) {
    __shared__ float sm_m[4][32];
    __shared__ float sm_l[4][32];
    __shared__ _Float16 sm_o[4][128][34];   // [wave][h][q], +2 pad

    const int t    = threadIdx.x;
    const int lane = t & 63, wid = t >> 6;
    const int lo = lane & 15, hi = lane >> 4;

    const int i   = blockIdx.x;            // 0..511
    const int b   = (i >> 1) & 3;          // batch -> XCD pair {2b, 2b+1}
    const int qtr = ((i >> 3) << 1) | (i & 1);          // 0..127
    const int qt  = (qtr < 64) ? qtr : (191 - qtr);     // zigzag: i & i+256 complement
    const int q0  = qt << 5;               // 32 queries: q0..q0+31

    const _Float16* Qb = Qf  + (size_t)b * (S_ * H_);
    const _Float16* Kb = Kf  + (size_t)b * (S_ * H_);
    const _Float16* Vb = VTf + (size_t)b * (H_ * S_);

    half8 qfa[4], qfb[4];
#pragma unroll
    for (int kk = 0; kk < 4; ++kk) {
        qfa[kk] = *(const half8*)(Qb + (size_t)(q0 + lo) * H_ + kk * 32 + hi * 8);
        qfb[kk] = *(const half8*)(Qb + (size_t)(q0 + 16 + lo) * H_ + kk * 32 + hi * 8);
    }

    float4v oa[8], ob[8];
#pragma unroll
    for (int hc = 0; hc < 8; ++hc) { oa[hc] = {0.f,0.f,0.f,0.f}; ob[hc] = {0.f,0.f,0.f,0.f}; }
    float ma = -1e30f, la = 0.f, mb = -1e30f, lb = 0.f;

    const int permbase = ((lo >> 2) << 3) + (lo & 3);   // key row permutation
    const int ntiles = qt + 1;                          // keys 0..q0+31, 32/tile

    for (int tt = wid; tt < ntiles; tt += 4) {
        const int k0 = tt << 5;
        float4v s0a = {0.f,0.f,0.f,0.f}, s1a = {0.f,0.f,0.f,0.f};
        float4v s0b = {0.f,0.f,0.f,0.f}, s1b = {0.f,0.f,0.f,0.f};
        const _Float16* Kr0 = Kb + (size_t)(k0 + permbase) * H_;
        const _Float16* Kr1 = Kr0 + 4 * H_;
#pragma unroll
        for (int kk = 0; kk < 4; ++kk) {
            half8 kf0 = *(const half8*)(Kr0 + kk * 32 + hi * 8);
            half8 kf1 = *(const half8*)(Kr1 + kk * 32 + hi * 8);
            s0a = __builtin_amdgcn_mfma_f32_16x16x32_f16(kf0, qfa[kk], s0a, 0, 0, 0);
            s0b = __builtin_amdgcn_mfma_f32_16x16x32_f16(kf0, qfb[kk], s0b, 0, 0, 0);
            s1a = __builtin_amdgcn_mfma_f32_16x16x32_f16(kf1, qfa[kk], s1a, 0, 0, 0);
            s1b = __builtin_amdgcn_mfma_f32_16x16x32_f16(kf1, qfb[kk], s1b, 0, 0, 0);
        }
        // s0x[j] = S[q][k0+8hi+j], s1x[j] = S[q][k0+8hi+4+j]
        if (tt == qt) {   // diagonal tile: only place masking is needed
#pragma unroll
            for (int j = 0; j < 4; ++j) {
                const int c0 = 8 * hi + j, c1 = 8 * hi + 4 + j;
                if (c0 > lo)      s0a[j] = -INFINITY;
                if (c1 > lo)      s1a[j] = -INFINITY;
                if (c0 > 16 + lo) s0b[j] = -INFINITY;
                if (c1 > 16 + lo) s1b[j] = -INFINITY;
            }
        }
        // ---- softmax a ----
        float tmax = fmaxf(fmaxf(fmaxf(s0a[0], s0a[1]), fmaxf(s0a[2], s0a[3])),
                           fmaxf(fmaxf(s1a[0], s1a[1]), fmaxf(s1a[2], s1a[3])));
        tmax = fmaxf(tmax, __shfl_xor(tmax, 16));
        tmax = fmaxf(tmax, __shfl_xor(tmax, 32));
        float mnew  = fmaxf(fmaxf(ma, tmax), -1e30f);
        float alpha = __expf(ma - mnew);
        float pa0 = __expf(s0a[0]-mnew), pa1 = __expf(s0a[1]-mnew);
        float pa2 = __expf(s0a[2]-mnew), pa3 = __expf(s0a[3]-mnew);
        float pa4 = __expf(s1a[0]-mnew), pa5 = __expf(s1a[1]-mnew);
        float pa6 = __expf(s1a[2]-mnew), pa7 = __expf(s1a[3]-mnew);
        float ts = ((pa0+pa1)+(pa2+pa3)) + ((pa4+pa5)+(pa6+pa7));
        ts += __shfl_xor(ts, 16);
        ts += __shfl_xor(ts, 32);
        la = la * alpha + ts;
        ma = mnew;
#pragma unroll
        for (int hc = 0; hc < 8; ++hc) {
            oa[hc][0] *= alpha; oa[hc][1] *= alpha;
            oa[hc][2] *= alpha; oa[hc][3] *= alpha;
        }
        half8 pfa;
        pfa[0]=(_Float16)pa0; pfa[1]=(_Float16)pa1; pfa[2]=(_Float16)pa2; pfa[3]=(_Float16)pa3;
        pfa[4]=(_Float16)pa4; pfa[5]=(_Float16)pa5; pfa[6]=(_Float16)pa6; pfa[7]=(_Float16)pa7;
        // ---- softmax b (independent chain) ----
        float tmaxb = fmaxf(fmaxf(fmaxf(s0b[0], s0b[1]), fmaxf(s0b[2], s0b[3])),
                            fmaxf(fmaxf(s1b[0], s1b[1]), fmaxf(s1b[2], s1b[3])));
        tmaxb = fmaxf(tmaxb, __shfl_xor(tmaxb, 16));
        tmaxb = fmaxf(tmaxb, __shfl_xor(tmaxb, 32));
        float mnewb  = fmaxf(fmaxf(mb, tmaxb), -1e30f);
        float alphab = __expf(mb - mnewb);
        float pb0 = __expf(s0b[0]-mnewb), pb1 = __expf(s0b[1]-mnewb);
        float pb2 = __expf(s0b[2]-mnewb), pb3 = __expf(s0b[3]-mnewb);
        float pb4 = __expf(s1b[0]-mnewb), pb5 = __expf(s1b[1]-mnewb);
        float pb6 = __expf(s1b[2]-mnewb), pb7 = __expf(s1b[3]-mnewb);
        float tsb = ((pb0+pb1)+(pb2+pb3)) + ((pb4+pb5)+(pb6+pb7));
        tsb += __shfl_xor(tsb, 16);
        tsb += __shfl_xor(tsb, 32);
        lb = lb * alphab + tsb;
        mb = mnewb;
#pragma unroll
        for (int hc = 0; hc < 8; ++hc) {
            ob[hc][0] *= alphab; ob[hc][1] *= alphab;
            ob[hc][2] *= alphab; ob[hc][3] *= alphab;
        }
        half8 pfb;
        pfb[0]=(_Float16)pb0; pfb[1]=(_Float16)pb1; pfb[2]=(_Float16)pb2; pfb[3]=(_Float16)pb3;
        pfb[4]=(_Float16)pb4; pfb[5]=(_Float16)pb5; pfb[6]=(_Float16)pb6; pfb[7]=(_Float16)pb7;
        // ---- PV: V fragments shared between both sub-tiles ----
#pragma unroll
        for (int hc = 0; hc < 8; ++hc) {
            half8 vf = *(const half8*)(Vb + (size_t)(hc * 16 + lo) * S_ + k0 + hi * 8);
            oa[hc] = __builtin_amdgcn_mfma_f32_16x16x32_f16(vf, pfa, oa[hc], 0, 0, 0);
            ob[hc] = __builtin_amdgcn_mfma_f32_16x16x32_f16(vf, pfb, ob[hc], 0, 0, 0);
        }
    }

    // ---- merge the 4 KV-split partials (l-normalized f16) ----
    const float inva = (la > 0.f) ? 1.f / la : 0.f;
    const float invb = (lb > 0.f) ? 1.f / lb : 0.f;
    sm_m[wid][lo] = ma;      sm_l[wid][lo] = la;
    sm_m[wid][16 + lo] = mb; sm_l[wid][16 + lo] = lb;
#pragma unroll
    for (int hc = 0; hc < 8; ++hc)
#pragma unroll
        for (int j = 0; j < 4; ++j) {
            const int h = hc * 16 + 4 * hi + j;
            sm_o[wid][h][lo]      = (_Float16)(oa[hc][j] * inva);
            sm_o[wid][h][16 + lo] = (_Float16)(ob[hc][j] * invb);
        }
    __syncthreads();

#pragma unroll
    for (int qh = 0; qh < 2; ++qh) {
        const int q = qh * 16 + lo;
        const float m0_ = sm_m[0][q], m1_ = sm_m[1][q];
        const float m2_ = sm_m[2][q], m3_ = sm_m[3][q];
        const float M = fmaxf(fmaxf(m0_, m1_), fmaxf(m2_, m3_));
        const float c0 = __expf(m0_ - M) * sm_l[0][q];
        const float c1 = __expf(m1_ - M) * sm_l[1][q];
        const float c2 = __expf(m2_ - M) * sm_l[2][q];
        const float c3 = __expf(m3_ - M) * sm_l[3][q];
        const float invL = 1.f / (c0 + c1 + c2 + c3);
#pragma unroll
        for (int g = 0; g < 2; ++g) {
            const int hc = wid * 2 + g;
            float4v ov;
#pragma unroll
            for (int j = 0; j < 4; ++j) {
                const int h = hc * 16 + 4 * hi + j;
                ov[j] = (c0 * (float)sm_o[0][h][q] + c1 * (float)sm_o[1][h][q] +
                         c2 * (float)sm_o[2][h][q] + c3 * (float)sm_o[3][h][q]) * invL;
            }
            *(float4v*)(Out + ((size_t)b * S_ + q0 + q) * H_ + hc * 16 + 4 * hi) = ov;
        }
    }
}

extern "C" void kernel_launch(void* const* d_in, const int* in_sizes, int n_in,
                              void* d_out, int out_size, void* d_ws, size_t ws_size,
                              hipStream_t stream) {
    const float* x  = (const float*)d_in[0];
    const float* Wq = (const float*)d_in[1];
    const float* bq = (const float*)d_in[2];
    const float* Wk = (const float*)d_in[3];
    const float* bk = (const float*)d_in[4];
    const float* Wv = (const float*)d_in[5];
    const float* bv = (const float*)d_in[6];
    float* out = (float*)d_out;   // reference output dtype = float32

    char* ws = (char*)d_ws;
    _Float16* WT  = (_Float16*)ws;                       //   786,432 B
    _Float16* Qf  = (_Float16*)(ws + 786432);            // 4,194,304 B
    _Float16* Kf  = (_Float16*)(ws + 786432 + 4194304);
    _Float16* VTf = (_Float16*)(ws + 786432 + 8388608);  // total ~12.8 MB

    hipLaunchKernelGGL(k_cvt_w, dim3(512, 3), dim3(256), 0, stream, Wq, Wk, Wv, WT);
    hipLaunchKernelGGL(k_proj, dim3(3, 128), dim3(256), 0, stream,
                       x, WT, bq, bk, bv, Qf, Kf, VTf);
    hipLaunchKernelGGL(k_attn, dim3(512), dim3(256), 0, stream, Qf, Kf, VTf, out);
}